// Round 3
// baseline (359.816 us; speedup 1.0000x reference)
//
#include <hip/hip_runtime.h>
#include <hip/hip_bf16.h>
#include <math.h>

#define LEN 128
#define NCELLS_PAD 8448      // padded triangular chart: OFFp(127)+128 < 8448
#define TOTAL 349504         // sum_{l=1}^{127} (128-l)*l
#define NCONSTR 8
#define BONUS 1000.0f
#define NT 512

// Padded level offsets: OFFp(n) = OFFu(n) + n = n*(259-n)/2  (+1 cell pad per level)
__device__ __forceinline__ int OFFp(int n) { return (n * (259 - n)) >> 1; }

// Barrier WITHOUT vmcnt drain: only LDS (chart) writes must be ordered.
// Register prefetch loads stay in flight across the barrier (T4 discipline).
__device__ __forceinline__ void level_barrier() {
    __builtin_amdgcn_sched_barrier(0);
    asm volatile("s_waitcnt lgkmcnt(0)\n\ts_barrier" ::: "memory");
    __builtin_amdgcn_sched_barrier(0);
}

// DPP quad_perm cross-lane max (VALU pipe, no LDS traffic).
__device__ __forceinline__ float dpp_xor1_max(float v) {
    int r = __builtin_amdgcn_update_dpp(0, __float_as_int(v), 0xB1, 0xF, 0xF, true); // [1,0,3,2]
    return fmaxf(v, __int_as_float(r));
}
__device__ __forceinline__ float dpp_xor2_max(float v) {
    int r = __builtin_amdgcn_update_dpp(0, __float_as_int(v), 0x4E, 0xF, 0xF, true); // [2,3,0,1]
    return fmaxf(v, __int_as_float(r));
}

template<int LG>
__device__ __forceinline__ void redmax2(float& a, float& b) {
    #pragma unroll
    for (int mm = (1 << LG) >> 1; mm >= 4; mm >>= 1) {
        a = fmaxf(a, __shfl_xor(a, mm));
        b = fmaxf(b, __shfl_xor(b, mm));
    }
    if constexpr (LG >= 2) { a = dpp_xor2_max(a); b = dpp_xor2_max(b); }
    if constexpr (LG >= 1) { a = dpp_xor1_max(a); b = dpp_xor1_max(b); }
}

// One CKY level. LG = log2(threads per cell), LG2 = same for next level
// (-1: no prefetch). MJ/MJ2 = compile-time unroll caps; runtime uniform
// `break` keeps issue count proportional to the true trip count while
// register indices stay compile-time (no scratch).
template<int LG, int LG2, int MJ, int MJ2>
__device__ __forceinline__ void lstep(const int level, int& soff,
        const float* __restrict__ g, float2* __restrict__ chart,
        float (&rcur)[16], float (&rnxt)[16], const int tid)
{
    const int N = level;
    const int L = LEN - level;
    constexpr int T = 1 << LG;
    const int pos = tid >> LG;
    const int sub = tid & (T - 1);
    const int soff_n = soff + L * N;

    // ---- issue next level's score loads into registers (exact count) ----
    if constexpr (LG2 >= 0) {
        const int N2 = level + 1;
        const int L2 = L - 1;
        constexpr int T2 = 1 << LG2;
        const int pos2 = tid >> LG2;
        const int sub2 = tid & (T2 - 1);
        const int jm2  = (N2 + T2 - 1) >> LG2;            // uniform
        const int jml2 = (N2 - sub2 + T2 - 1) >> LG2;     // per-lane valid count
        if (pos2 < L2) {
            const float* __restrict__ gp = g + soff_n + pos2 * N2 + sub2;
            #pragma unroll
            for (int j = 0; j < MJ2; j++) {
                if (j >= jm2) break;                      // uniform scalar branch
                if (j < jml2) rnxt[j] = gp[j * T2];       // masked tail load
            }
        }
    }

    // ---- compute this level: chart (LDS, byte-offset induction) + rcur ----
    float bp = -INFINITY, bc = -INFINITY;
    if (pos < L) {
        const int jm  = (N + T - 1) >> LG;                // uniform trip count
        const int jml = (N - sub + T - 1) >> LG;          // per-lane valid count
        const int m0  = level - 1 - sub;
        // byte offsets into chart (float2 = 8B); quadratic induction
        int li = (OFFp(sub) + pos) << 3;
        int ri = (OFFp(m0) + pos + sub + 1) << 3;
        int dl = ((T * (259 - 2 * sub - T)) / 2) << 3;
        int dr = ((T * (2 * m0 - 257 - T)) / 2) << 3;
        const char* __restrict__ cb = (const char*)chart;
        #pragma unroll
        for (int j = 0; j < MJ; j++) {
            if (j >= jm) break;                           // uniform scalar branch
            const bool v = (j < jml);                     // per-lane tail guard
            const int riu = v ? ri : 0;                   // ri can go negative on tail
            const float2 lv = *(const float2*)(cb + li);  // li always in-bounds
            const float2 rv = *(const float2*)(cb + riu);
            const float x = v ? rcur[j] : -INFINITY;
            bp = fmaxf(bp, lv.x + rv.x + x);
            bc = fmaxf(bc, lv.y + rv.y + x);
            li += dl; dl -= (T * T) << 3;
            ri += dr; dr -= (T * T) << 3;
        }
    }
    redmax2<LG>(bp, bc);
    if (pos < L && sub == 0) {
        const int q = OFFp(level) + pos;
        float2 c = chart[q];
        c.x += bp;
        c.y += bc;
        chart[q] = c;
    }
    level_barrier();
    soff = soff_n;
}

__global__ __launch_bounds__(NT)
void cky_fused_kernel(const float* __restrict__ scores,
                      const int* __restrict__ cpos,
                      float* __restrict__ ws)
{
    __shared__ float2 chart[NCELLS_PAD];   // .x = pred chart, .y = constr chart

    const int b   = blockIdx.x;
    const int tid = threadIdx.x;
    const float* __restrict__ g = scores + (size_t)b * TOTAL;

    float rA[16], rB[16];

    // ---- prefetch level 1 scores (N=1, LG=2 mapping) ----
    {
        const int pos = tid >> 2;
        const int sub = tid & 3;
        if (pos < 127 && sub == 0) rA[0] = g[pos];
    }
    // ---- constraint remap to padded layout: cell level n -> index p + n ----
    int cp = -1;
    if (tid < NCONSTR) {
        const int p = cpos[b * NCONSTR + tid];            // in [128, 8256)
        const float sq = sqrtf((float)(66049 - 8 * p));   // exact at cell starts
        int n = (int)((257.0f - sq) * 0.5f);
        if (n < 1) n = 1;
        if (n > 127) n = 127;
        while (n < 127 && ((n + 1) * (256 - n)) / 2 <= p) n++;  // OFFu(n+1) <= p
        while (n > 1 && (n * (257 - n)) / 2 > p) n--;           // OFFu(n)   >  p
        cp = p + n;
    }

    // ---- init both charts (zero incl. padding; OOB-tail reads see 0.f) ----
    for (int i = tid; i < NCELLS_PAD; i += NT) chart[i] = make_float2(0.f, 0.f);
    level_barrier();
    if (tid < NCONSTR) chart[cp].y = BONUS;   // set (not add); duplicates benign
    level_barrier();

    int soff = 0;

    // Segments by compile-time TPP; parity alternates rA/rB prefetch buffers.
    #pragma unroll 1
    for (int l = 1; l <= 61; l += 2) {                 // levels 1..62 (L=127..66)
        lstep<2,2,16,16>(l,     soff, g, chart, rA, rB, tid);
        lstep<2,2,16,16>(l + 1, soff, g, chart, rB, rA, tid);
    }
    lstep<2,3,16,12>(63, soff, g, chart, rA, rB, tid); // L=65 -> next TPP=8
    #pragma unroll 1
    for (int l = 64; l <= 92; l += 2) {                // levels 64..93 (L=64..35)
        lstep<3,3,12,12>(l,     soff, g, chart, rB, rA, tid);
        lstep<3,3,12,12>(l + 1, soff, g, chart, rA, rB, tid);
    }
    lstep<3,3,12,12>(94, soff, g, chart, rB, rA, tid);
    lstep<3,4,12,7>(95,  soff, g, chart, rA, rB, tid); // L=33 -> next TPP=16
    #pragma unroll 1
    for (int l = 96; l <= 108; l += 2) {               // levels 96..109 (L=32..19)
        lstep<4,4,7,7>(l,     soff, g, chart, rB, rA, tid);
        lstep<4,4,7,7>(l + 1, soff, g, chart, rA, rB, tid);
    }
    lstep<4,4,7,7>(110, soff, g, chart, rB, rA, tid);
    lstep<4,5,7,4>(111, soff, g, chart, rA, rB, tid);  // L=17 -> next TPP=32
    #pragma unroll 1
    for (int l = 112; l <= 116; l += 2) {              // levels 112..117 (L=16..11)
        lstep<5,5,4,4>(l,     soff, g, chart, rB, rA, tid);
        lstep<5,5,4,4>(l + 1, soff, g, chart, rA, rB, tid);
    }
    lstep<5,5,4,4>(118, soff, g, chart, rB, rA, tid);
    lstep<5,6,4,2>(119, soff, g, chart, rA, rB, tid);  // L=9 -> next TPP=64
    #pragma unroll 1
    for (int l = 120; l <= 124; l += 2) {              // levels 120..125 (L=8..3)
        lstep<6,6,2,2>(l,     soff, g, chart, rB, rA, tid);
        lstep<6,6,2,2>(l + 1, soff, g, chart, rA, rB, tid);
    }
    lstep<6,6,2,2>(126, soff, g, chart, rB, rA, tid);
    lstep<6,-1,2,2>(127, soff, g, chart, rA, rB, tid); // root; no prefetch

    // ---- per-batch hinge contribution ----
    if (tid == 0) {
        const float2 f = chart[OFFp(127)];             // root cell (padded idx 8382)
        const float pred   = f.x;
        const float constr = f.y - BONUS * NCONSTR;
        const float diff   = pred - constr;
        const float mask   = (fabsf(diff) >= 0.001f) ? 1.f : 0.f;
        const float hinge  = fmaxf(1.0f + diff, 0.f) * mask;
        atomicAdd(ws + 0, hinge);
        atomicAdd(ws + 1, mask);
    }
}

__global__ void final_kernel(const float* __restrict__ ws, float* __restrict__ out) {
    const float h = ws[0];
    const float m = ws[1];
    out[0] = (m > 0.1f) ? (h / fmaxf(m, 1.f)) : h;
}

extern "C" void kernel_launch(void* const* d_in, const int* in_sizes, int n_in,
                              void* d_out, int out_size, void* d_ws, size_t ws_size,
                              hipStream_t stream) {
    const float* scores = (const float*)d_in[0];
    const int*   cpos   = (const int*)d_in[1];
    float* out = (float*)d_out;
    float* ws  = (float*)d_ws;

    hipMemsetAsync(ws, 0, 2 * sizeof(float), stream);
    cky_fused_kernel<<<dim3(256), dim3(NT), 0, stream>>>(scores, cpos, ws);
    final_kernel<<<dim3(1), dim3(1), 0, stream>>>(ws, out);
}

// Round 4
// 142.072 us; speedup vs baseline: 2.5326x; 2.5326x over previous
//
#include <hip/hip_runtime.h>
#include <hip/hip_bf16.h>
#include <math.h>

#define LEN 128
#define NCELLS 8256          // LEN*(LEN+1)/2
#define TOTAL 349504         // sum_{l=1}^{127} (128-l)*l
#define NCONSTR 8
#define BONUS 1000.0f
#define NT 512

// Barrier WITHOUT vmcnt drain: only LDS (chart) writes must be ordered.
// Register prefetch loads stay in flight across the barrier (T4 discipline).
__device__ __forceinline__ void level_barrier() {
    __builtin_amdgcn_sched_barrier(0);
    asm volatile("s_waitcnt lgkmcnt(0)\n\ts_barrier" ::: "memory");
    __builtin_amdgcn_sched_barrier(0);
}

// DPP quad_perm cross-lane max (VALU pipe, no LDS traffic).
__device__ __forceinline__ float dpp_xor1_max(float v) {
    int r = __builtin_amdgcn_update_dpp(0, __float_as_int(v), 0xB1, 0xF, 0xF, true); // [1,0,3,2]
    return fmaxf(v, __int_as_float(r));
}
__device__ __forceinline__ float dpp_xor2_max(float v) {
    int r = __builtin_amdgcn_update_dpp(0, __float_as_int(v), 0x4E, 0xF, 0xF, true); // [2,3,0,1]
    return fmaxf(v, __int_as_float(r));
}

template<int LG>
__device__ __forceinline__ void redmax2(float& a, float& b) {
    #pragma unroll
    for (int mm = (1 << LG) >> 1; mm >= 4; mm >>= 1) {
        a = fmaxf(a, __shfl_xor(a, mm));
        b = fmaxf(b, __shfl_xor(b, mm));
    }
    if constexpr (LG >= 2) { a = dpp_xor2_max(a); b = dpp_xor2_max(b); }
    if constexpr (LG >= 1) { a = dpp_xor1_max(a); b = dpp_xor1_max(b); }
}

// One CKY level. LG = log2(threads/cell); JM = exact ceil(N/TPP) (compile-time,
// fully unrolled, NO breaks). Phase 1: compute all independent addresses and
// issue all 2*JM ds_read_b64 into register arrays. Phase 2: consume.
// Per-lane tail handled by cndmask clamp (no exec-mask branches on the
// critical path). LG2/JM2: prefetch next level's scores into rnxt (guarded
// per-lane; loads stay in flight across the barrier).
template<int LG, int LG2, int JM, int JM2>
__device__ __forceinline__ void lstep(const int level, int& soff,
        const float* __restrict__ g, float2* __restrict__ chart,
        float (&rcur)[16], float (&rnxt)[16], const int tid)
{
    const int N = level;
    const int L = LEN - level;
    constexpr int T = 1 << LG;
    const int pos = tid >> LG;
    const int sub = tid & (T - 1);
    const int soff_n = soff + L * N;

    // ---- issue next level's score loads (consumed after next barrier) ----
    if constexpr (LG2 >= 0) {
        constexpr int T2 = 1 << LG2;
        const int N2 = level + 1;
        const int L2 = L - 1;
        const int pos2 = tid >> LG2;
        const int sub2 = tid & (T2 - 1);
        if (pos2 < L2) {
            const float* __restrict__ gp = g + soff_n + pos2 * N2 + sub2;
            #pragma unroll
            for (int j = 0; j < JM2; j++) {
                if (sub2 + j * T2 < N2) rnxt[j] = gp[j * T2];
            }
        }
    }

    // ---- compute this level ----
    float bp = -INFINITY, bc = -INFINITY;
    if (pos < L) {
        const int jml = (N - sub + T - 1) >> LG;   // per-lane valid trip count
        float2 lv[JM], rv[JM];
        float  xs[JM];
        #pragma unroll
        for (int j = 0; j < JM; j++) {
            const int n = sub + j * T;             // compile-time j: independent
            const int m = level - 1 - n;
            const bool v = (j < jml);
            const int l_idx = ((n * (257 - n)) >> 1) + pos;      // always in-bounds
            int r_idx = ((m * (257 - m)) >> 1) + pos + n + 1;    // can go negative
            r_idx = v ? r_idx : 0;
            lv[j] = chart[l_idx];
            rv[j] = chart[r_idx];
            xs[j] = v ? rcur[j] : -INFINITY;
        }
        #pragma unroll
        for (int j = 0; j < JM; j++) {
            bp = fmaxf(bp, lv[j].x + rv[j].x + xs[j]);
            bc = fmaxf(bc, lv[j].y + rv[j].y + xs[j]);
        }
    }
    redmax2<LG>(bp, bc);
    if (pos < L && sub == 0) {
        const int q = ((level * (257 - level)) >> 1) + pos;
        float2 c = chart[q];
        c.x += bp;
        c.y += bc;
        chart[q] = c;
    }
    level_barrier();
    soff = soff_n;
}

// 4 levels at TPP=4 with exact JM=K (levels 4K-3..4K); prefetch JM2=K+1,
// per-lane guarded (dead iterations cost one execz-skipped branch).
template<int K>
__device__ __forceinline__ void seg4(int& soff, const float* __restrict__ g,
        float2* __restrict__ chart, float (&rA)[16], float (&rB)[16], const int tid)
{
    const int l0 = 4 * K - 3;
    #pragma unroll 1
    for (int l = l0; l < l0 + 4; l += 2) {
        lstep<2, 2, K, K + 1>(l,     soff, g, chart, rA, rB, tid);
        lstep<2, 2, K, K + 1>(l + 1, soff, g, chart, rB, rA, tid);
    }
}

__global__ __launch_bounds__(NT)
void cky_fused_kernel(const float* __restrict__ scores,
                      const int* __restrict__ cpos,
                      float* __restrict__ ws)
{
    __shared__ float2 chart[NCELLS];   // .x = pred chart, .y = constr chart

    const int b   = blockIdx.x;
    const int tid = threadIdx.x;
    const float* __restrict__ g = scores + (size_t)b * TOTAL;

    float rA[16], rB[16];

    // ---- prefetch level 1 scores (N=1, TPP=4 mapping) ----
    {
        const int pos = tid >> 2;
        const int sub = tid & 3;
        if (pos < 127 && sub == 0) rA[0] = g[pos];
    }
    int cp = -1;
    if (tid < NCONSTR) cp = cpos[b * NCONSTR + tid];

    // ---- init both charts ----
    for (int i = tid; i < NCELLS; i += NT) chart[i] = make_float2(0.f, 0.f);
    level_barrier();
    if (tid < NCONSTR) chart[cp].y = BONUS;   // set (not add); duplicates benign
    level_barrier();

    int soff = 0;

    // ---- TPP=4: levels 1..60 via exact-JM segments ----
    seg4<1>(soff, g, chart, rA, rB, tid);
    seg4<2>(soff, g, chart, rA, rB, tid);
    seg4<3>(soff, g, chart, rA, rB, tid);
    seg4<4>(soff, g, chart, rA, rB, tid);
    seg4<5>(soff, g, chart, rA, rB, tid);
    seg4<6>(soff, g, chart, rA, rB, tid);
    seg4<7>(soff, g, chart, rA, rB, tid);
    seg4<8>(soff, g, chart, rA, rB, tid);
    seg4<9>(soff, g, chart, rA, rB, tid);
    seg4<10>(soff, g, chart, rA, rB, tid);
    seg4<11>(soff, g, chart, rA, rB, tid);
    seg4<12>(soff, g, chart, rA, rB, tid);
    seg4<13>(soff, g, chart, rA, rB, tid);
    seg4<14>(soff, g, chart, rA, rB, tid);
    seg4<15>(soff, g, chart, rA, rB, tid);
    // ---- TPP=4 tail: levels 61..63 (JM=16) ----
    lstep<2,2,16,16>(61, soff, g, chart, rA, rB, tid);
    lstep<2,2,16,16>(62, soff, g, chart, rB, rA, tid);
    lstep<2,3,16,8>(63, soff, g, chart, rA, rB, tid);   // next TPP=8
    // ---- TPP=8: levels 64..95 ----
    lstep<3,3,8,9>(64, soff, g, chart, rB, rA, tid);
    #pragma unroll 1
    for (int l = 65; l < 72; l += 2) {                  // 65..72 (JM=9)
        lstep<3,3,9,10>(l,     soff, g, chart, rA, rB, tid);
        lstep<3,3,9,10>(l + 1, soff, g, chart, rB, rA, tid);
    }
    #pragma unroll 1
    for (int l = 73; l < 80; l += 2) {                  // 73..80 (JM=10)
        lstep<3,3,10,11>(l,     soff, g, chart, rA, rB, tid);
        lstep<3,3,10,11>(l + 1, soff, g, chart, rB, rA, tid);
    }
    #pragma unroll 1
    for (int l = 81; l < 88; l += 2) {                  // 81..88 (JM=11)
        lstep<3,3,11,12>(l,     soff, g, chart, rA, rB, tid);
        lstep<3,3,11,12>(l + 1, soff, g, chart, rB, rA, tid);
    }
    #pragma unroll 1
    for (int l = 89; l < 94; l += 2) {                  // 89..94 (JM=12)
        lstep<3,3,12,12>(l,     soff, g, chart, rA, rB, tid);
        lstep<3,3,12,12>(l + 1, soff, g, chart, rB, rA, tid);
    }
    lstep<3,4,12,6>(95, soff, g, chart, rA, rB, tid);   // next TPP=16
    // ---- TPP=16: levels 96..111 ----
    lstep<4,4,6,7>(96, soff, g, chart, rB, rA, tid);
    #pragma unroll 1
    for (int l = 97; l < 110; l += 2) {                 // 97..110 (JM=7)
        lstep<4,4,7,7>(l,     soff, g, chart, rA, rB, tid);
        lstep<4,4,7,7>(l + 1, soff, g, chart, rB, rA, tid);
    }
    lstep<4,5,7,4>(111, soff, g, chart, rA, rB, tid);   // next TPP=32
    // ---- TPP=32: levels 112..119 ----
    lstep<5,5,4,4>(112, soff, g, chart, rB, rA, tid);
    #pragma unroll 1
    for (int l = 113; l < 118; l += 2) {                // 113..118
        lstep<5,5,4,4>(l,     soff, g, chart, rA, rB, tid);
        lstep<5,5,4,4>(l + 1, soff, g, chart, rB, rA, tid);
    }
    lstep<5,6,4,2>(119, soff, g, chart, rA, rB, tid);   // next TPP=64
    // ---- TPP=64: levels 120..127 ----
    lstep<6,6,2,2>(120, soff, g, chart, rB, rA, tid);
    #pragma unroll 1
    for (int l = 121; l < 126; l += 2) {                // 121..126
        lstep<6,6,2,2>(l,     soff, g, chart, rA, rB, tid);
        lstep<6,6,2,2>(l + 1, soff, g, chart, rB, rA, tid);
    }
    lstep<6,-1,2,2>(127, soff, g, chart, rA, rB, tid);  // root; no prefetch

    // ---- per-batch hinge contribution ----
    if (tid == 0) {
        const float2 f = chart[NCELLS - 1];
        const float pred   = f.x;
        const float constr = f.y - BONUS * NCONSTR;
        const float diff   = pred - constr;
        const float mask   = (fabsf(diff) >= 0.001f) ? 1.f : 0.f;
        const float hinge  = fmaxf(1.0f + diff, 0.f) * mask;
        atomicAdd(ws + 0, hinge);
        atomicAdd(ws + 1, mask);
    }
}

__global__ void final_kernel(const float* __restrict__ ws, float* __restrict__ out) {
    const float h = ws[0];
    const float m = ws[1];
    out[0] = (m > 0.1f) ? (h / fmaxf(m, 1.f)) : h;
}

extern "C" void kernel_launch(void* const* d_in, const int* in_sizes, int n_in,
                              void* d_out, int out_size, void* d_ws, size_t ws_size,
                              hipStream_t stream) {
    const float* scores = (const float*)d_in[0];
    const int*   cpos   = (const int*)d_in[1];
    float* out = (float*)d_out;
    float* ws  = (float*)d_ws;

    hipMemsetAsync(ws, 0, 2 * sizeof(float), stream);
    cky_fused_kernel<<<dim3(256), dim3(NT), 0, stream>>>(scores, cpos, ws);
    final_kernel<<<dim3(1), dim3(1), 0, stream>>>(ws, out);
}